// Round 6
// baseline (587.875 us; speedup 1.0000x reference)
//
#include <hip/hip_runtime.h>

// EUNN: 256 layers; each layer = rotation on even pairs (2i,2i+1), then
// rotation on odd pairs (2i+1,2i+2 mod H).
// Pair math: y0 = e^{i*phi} (ct*u - st*v); y1 = st*u + ct*v.

#define H_DIM 1024
#define C2 256
#define RPW 2   // batch rows per wave

// coef layout: [c][j][lane] as float4 (ct, st, cp, sp); j in [0,16):
//   j=0..7  : phase A pair (local 2j, 2j+1) of lane      (global pair 8*lane+j)
//   j=8..14 : phase B internal pair (local 2j-15, 2j-14) (global pair 8*lane+j-8)
//   j=15    : phase B boundary pair (lane elem15, next lane's elem0)
// flat float4 index: (c*16 + j)*64 + lane,  16 KB per layer, 4 MB total.

__global__ __launch_bounds__(256) void eunn_coef_kernel(
    const float* __restrict__ phi0, const float* __restrict__ theta0,
    const float* __restrict__ phi1, const float* __restrict__ theta1,
    float4* __restrict__ coef) {
    int t = blockIdx.x * 256 + threadIdx.x;   // [0, 262144)
    int c = t & 255;                          // layer in low bits -> coalesced reads
    int ip = t >> 8;                          // [0,1024)
    int i = ip >> 1;                          // pair index [0,512)
    int p = ip & 1;                           // phase
    const float* phi   = p ? phi1   : phi0;
    const float* theta = p ? theta1 : theta0;
    float ph = phi[i * C2 + c];
    float th = theta[i * C2 + c];
    float sp, cp, st, ct;
    __sincosf(ph, &sp, &cp);
    __sincosf(th, &st, &ct);
    int j = (i & 7) + 8 * p;                  // j slot: A pairs 0..7, B pairs 8..15
    int l = i >> 3;
    coef[((c * 16) + j) * 64 + l] = make_float4(ct, st, cp, sp);
}

__device__ __forceinline__ void rot_pair(const float4 q,
                                         float& ur, float& ui,
                                         float& wr, float& wi) {
    // q = (ct, st, cp, sp)
    float ar = fmaf(-q.y, wr, q.x * ur);   // ct*u - st*v (real part)
    float ai = fmaf(-q.y, wi, q.x * ui);
    float br = fmaf( q.x, wr, q.y * ur);   // st*u + ct*v
    float bi = fmaf( q.x, wi, q.y * ui);
    ur = fmaf(-q.w, ai, q.z * ar);         // e^{i phi} * a
    ui = fmaf( q.w, ar, q.z * ai);
    wr = br;
    wi = bi;
}

// One layer: prefetch layer CNXT's 16 coef quads into QNXT (VMEM issued up
// front, consumed next half-iteration => ~1 full layer of latency slack),
// then compute the current layer from QCUR. Written as a macro so both
// buffers are plain local arrays with constant indices only (R2 post-mortem:
// lambdas/pointer-passed arrays defeat SROA -> scratch spills -> 2.5x).
#define LAYER_BODY(QCUR, QNXT, CNXT)                                          \
    {                                                                         \
        const float4* can = cl + (size_t)(CNXT) * 1024;                       \
        _Pragma("unroll")                                                     \
        for (int j = 0; j < 16; ++j) QNXT[j] = can[j * 64];                   \
        float4 qq = QCUR[15];                                                 \
        float qpx = __shfl(qq.x, (lane + 63) & 63);                           \
        float qpy = __shfl(qq.y, (lane + 63) & 63);                           \
        _Pragma("unroll")                                                     \
        for (int r = 0; r < RPW; ++r) {                                       \
            rot_pair(QCUR[0], vr[r][0],  vi[r][0],  vr[r][1],  vi[r][1]);     \
            rot_pair(QCUR[7], vr[r][14], vi[r][14], vr[r][15], vi[r][15]);    \
        }                                                                     \
        float nbr[RPW], nbi[RPW], pbr[RPW], pbi[RPW];                         \
        _Pragma("unroll")                                                     \
        for (int r = 0; r < RPW; ++r) {                                       \
            nbr[r] = __shfl(vr[r][0],  (lane + 1)  & 63);                     \
            nbi[r] = __shfl(vi[r][0],  (lane + 1)  & 63);                     \
            pbr[r] = __shfl(vr[r][15], (lane + 63) & 63);                     \
            pbi[r] = __shfl(vi[r][15], (lane + 63) & 63);                     \
        }                                                                     \
        _Pragma("unroll")                                                     \
        for (int j = 1; j < 7; ++j) {                                         \
            _Pragma("unroll")                                                 \
            for (int r = 0; r < RPW; ++r) {                                   \
                rot_pair(QCUR[j], vr[r][2 * j],     vi[r][2 * j],             \
                                  vr[r][2 * j + 1], vi[r][2 * j + 1]);        \
            }                                                                 \
        }                                                                     \
        _Pragma("unroll")                                                     \
        for (int j = 0; j < 7; ++j) {                                         \
            _Pragma("unroll")                                                 \
            for (int r = 0; r < RPW; ++r) {                                   \
                rot_pair(QCUR[8 + j], vr[r][2 * j + 1], vi[r][2 * j + 1],     \
                                      vr[r][2 * j + 2], vi[r][2 * j + 2]);    \
            }                                                                 \
        }                                                                     \
        _Pragma("unroll")                                                     \
        for (int r = 0; r < RPW; ++r) {                                       \
            float ar = fmaf(-qq.y, nbr[r], qq.x * vr[r][15]);                 \
            float ai = fmaf(-qq.y, nbi[r], qq.x * vi[r][15]);                 \
            vr[r][15] = fmaf(-qq.w, ai, qq.z * ar);                           \
            vi[r][15] = fmaf( qq.w, ar, qq.z * ai);                           \
            float b0r = fmaf(qpx, vr[r][0], qpy * pbr[r]);                    \
            float b0i = fmaf(qpx, vi[r][0], qpy * pbi[r]);                    \
            vr[r][0] = b0r; vi[r][0] = b0i;                                   \
        }                                                                     \
    }

// NOTE (R3 post-mortem): keep min-waves at 2. (256,4) capped VGPRs at 128 and
// the compiler squeezed the 64-float state through extra moves -> 526us.
// (256,2) gives the 256-VGPR budget this double-buffered version needs.
__global__ __launch_bounds__(256, 2) void eunn_main_kernel(
    const float* __restrict__ x,
    const float4* __restrict__ coef,
    float* __restrict__ out) {
    const int lane = threadIdx.x & 63;
    const int wave = threadIdx.x >> 6;
    const int row0 = (blockIdx.x * 4 + wave) * RPW;

    // lane owns complex elements [16*lane, 16*lane+16) of each of its RPW rows
    float vr[RPW][16], vi[RPW][16];

#pragma unroll
    for (int r = 0; r < RPW; ++r) {
        const float4* src = (const float4*)(x + (size_t)(row0 + r) * (H_DIM * 2)) + lane * 8;
#pragma unroll
        for (int m = 0; m < 8; ++m) {
            float4 f = src[m];
            vr[r][2 * m]     = f.x; vi[r][2 * m]     = f.y;
            vr[r][2 * m + 1] = f.z; vi[r][2 * m + 1] = f.w;
        }
    }

    const float4* cl = coef + lane;   // lane-offset base

    // double-buffered per-layer coefficients, fully register-resident
    float4 qa[16], qb[16];
#pragma unroll
    for (int j = 0; j < 16; ++j) qa[j] = cl[j * 64];   // layer 0

#pragma unroll 1
    for (int c = 0; c < C2; c += 2) {
        LAYER_BODY(qa, qb, c + 1)              // compute layer c, prefetch c+1
        LAYER_BODY(qb, qa, (c + 2) & 255)      // compute layer c+1, prefetch c+2
                                               // (c=254 wraps to a dummy reload of layer 0)
    }

#pragma unroll
    for (int r = 0; r < RPW; ++r) {
        float4* dst = (float4*)(out + (size_t)(row0 + r) * (H_DIM * 2)) + lane * 8;
#pragma unroll
        for (int m = 0; m < 8; ++m) {
            dst[m] = make_float4(vr[r][2 * m],     vi[r][2 * m],
                                 vr[r][2 * m + 1], vi[r][2 * m + 1]);
        }
    }
}

extern "C" void kernel_launch(void* const* d_in, const int* in_sizes, int n_in,
                              void* d_out, int out_size, void* d_ws, size_t ws_size,
                              hipStream_t stream) {
    const float* x      = (const float*)d_in[0];
    const float* phi0   = (const float*)d_in[1];
    const float* theta0 = (const float*)d_in[2];
    const float* phi1   = (const float*)d_in[3];
    const float* theta1 = (const float*)d_in[4];
    float* out = (float*)d_out;
    float4* coef = (float4*)d_ws;   // 256 layers * 16 * 64 float4 = 4 MB

    // coefficients: 256 layers * 2 phases * 512 pairs = 262144 threads
    hipLaunchKernelGGL(eunn_coef_kernel, dim3(1024), dim3(256), 0, stream,
                       phi0, theta0, phi1, theta1, coef);

    // main: 4096 rows / (4 waves/block * RPW rows/wave) = 512 blocks
    hipLaunchKernelGGL(eunn_main_kernel, dim3(512), dim3(256), 0, stream,
                       x, coef, out);
}

// Round 7
// 434.422 us; speedup vs baseline: 1.3532x; 1.3532x over previous
//
#include <hip/hip_runtime.h>

// EUNN: 256 layers; each layer = rotation on even pairs (2i,2i+1), then
// rotation on odd pairs (2i+1,2i+2 mod H).
// Pair math: y0 = e^{i*phi} (ct*u - st*v); y1 = st*u + ct*v.
//
// Journal: R1 423us (RPW=4, grid 256, occupancy-limited). R2/R6: register
// double-buffer of coefs => allocator collapses to ~60 VGPR + AGPR/scratch
// churn => 546-1080us. DO NOT reintroduce coef double-buffers. R3: (256,4)
// launch bound squeezed VGPRs => 526us. R4: RPW=2, grid 512, (256,2),
// straight single-stream loads => 370us main, VALUBusy 64%. R5: LDS staging
// + per-layer __syncthreads => 431us (barrier couples waves). R7 (this):
// R4 structure + float2/packed-fp32 math + coalesced coef kernel.

#define H_DIM 1024
#define C2 256
#define RPW 2   // batch rows per wave

// coef layout: [c][j][lane] as float4 (ct, st, cp, sp); j in [0,16):
//   j=0..7  : phase A pair (local 2j, 2j+1) of lane
//   j=8..14 : phase B internal pair (local 2j-15, 2j-14)
//   j=15    : phase B boundary pair (lane elem15, next lane's elem0)
// flat float4 index: (c*16 + j)*64 + lane,  16 KB per layer, 4 MB total.

__global__ __launch_bounds__(256) void eunn_coef_kernel(
    const float* __restrict__ phi0, const float* __restrict__ theta0,
    const float* __restrict__ phi1, const float* __restrict__ theta1,
    float4* __restrict__ coef) {
    int t = blockIdx.x * 256 + threadIdx.x;   // [0, 262144)
    int c = t & 255;                          // layer in low bits -> coalesced reads
    int ip = t >> 8;                          // [0,1024)
    int i = ip >> 1;                          // pair index [0,512)
    int p = ip & 1;                           // phase
    const float* phi   = p ? phi1   : phi0;
    const float* theta = p ? theta1 : theta0;
    float ph = phi[i * C2 + c];
    float th = theta[i * C2 + c];
    float sp, cp, st, ct;
    __sincosf(ph, &sp, &cp);
    __sincosf(th, &st, &ct);
    int j = (i & 7) + 8 * p;                  // j slot: A pairs 0..7, B pairs 8..15
    int l = i >> 3;
    coef[((c * 16) + j) * 64 + l] = make_float4(ct, st, cp, sp);
}

// Complex pair rotation with component-wise identical ops on (x=re, y=im) so
// the SLP vectorizer can form v_pk_mul_f32 / v_pk_fma_f32 (packed fp32).
__device__ __forceinline__ void rot_pair(const float4 q, float2& u, float2& w) {
    // q = (ct, st, cp, sp)
    float ax = fmaf(-q.y, w.x, q.x * u.x);   // a = ct*u - st*w   (both comps)
    float ay = fmaf(-q.y, w.y, q.x * u.y);
    float bx = fmaf( q.x, w.x, q.y * u.x);   // b = st*u + ct*w
    float by = fmaf( q.x, w.y, q.y * u.y);
    u.x = fmaf(-q.w, ay, q.z * ax);          // u = e^{i phi} * a
    u.y = fmaf( q.w, ax, q.z * ay);
    w.x = bx;
    w.y = by;
}

// NOTE (R3 post-mortem): keep min-waves at 2; (256,4) squeezes VGPRs and
// regresses. NOTE (R2/R6): no register coef double-buffer.
__global__ __launch_bounds__(256, 2) void eunn_main_kernel(
    const float* __restrict__ x,
    const float4* __restrict__ coef,
    float* __restrict__ out) {
    const int lane = threadIdx.x & 63;
    const int wave = threadIdx.x >> 6;
    const int row0 = (blockIdx.x * 4 + wave) * RPW;

    // lane owns complex elements [16*lane, 16*lane+16) of each of its RPW rows
    float2 v[RPW][16];

#pragma unroll
    for (int r = 0; r < RPW; ++r) {
        const float4* src = (const float4*)(x + (size_t)(row0 + r) * (H_DIM * 2)) + lane * 8;
#pragma unroll
        for (int m = 0; m < 8; ++m) {
            float4 f = src[m];
            v[r][2 * m]     = make_float2(f.x, f.y);
            v[r][2 * m + 1] = make_float2(f.z, f.w);
        }
    }

    const float4* cl = coef + lane;   // lane-offset base, strength-reduced in loop

#pragma unroll 1
    for (int c = 0; c < C2; ++c) {
        const float4* ca = cl + (size_t)c * 1024;

        // boundary coef for phase B, loaded up front; prev-lane copy via shuffle
        float4 qq = ca[15 * 64];
        float qpx = __shfl(qq.x, (lane + 63) & 63);   // prev lane's ct'
        float qpy = __shfl(qq.y, (lane + 63) & 63);   // prev lane's st'

        // --- phase A, boundary-adjacent pairs first (j=0 and j=7) so the
        // cross-lane shuffles can issue early and hide under the FMA work.
        {
            float4 q0 = ca[0 * 64];
            float4 q7 = ca[7 * 64];
#pragma unroll
            for (int r = 0; r < RPW; ++r) {
                rot_pair(q0, v[r][0],  v[r][1]);
                rot_pair(q7, v[r][14], v[r][15]);
            }
        }
        // post-phase-A elem0 / elem15 feed the phase-B boundary pair
        float nbr[RPW], nbi[RPW], pbr[RPW], pbi[RPW];
#pragma unroll
        for (int r = 0; r < RPW; ++r) {
            nbr[r] = __shfl(v[r][0].x,  (lane + 1)  & 63);   // next lane's elem0
            nbi[r] = __shfl(v[r][0].y,  (lane + 1)  & 63);
            pbr[r] = __shfl(v[r][15].x, (lane + 63) & 63);   // prev lane's elem15
            pbi[r] = __shfl(v[r][15].y, (lane + 63) & 63);
        }

        // --- phase A remaining pairs j=1..6
#pragma unroll
        for (int j = 1; j < 7; ++j) {
            float4 q = ca[j * 64];
#pragma unroll
            for (int r = 0; r < RPW; ++r) {
                rot_pair(q, v[r][2 * j], v[r][2 * j + 1]);
            }
        }

        // --- phase B internal pairs (local 2j+1, 2j+2), j=0..6
#pragma unroll
        for (int j = 0; j < 7; ++j) {
            float4 q = ca[(8 + j) * 64];
#pragma unroll
            for (int r = 0; r < RPW; ++r) {
                rot_pair(q, v[r][2 * j + 1], v[r][2 * j + 2]);
            }
        }

        // --- phase B boundary pair (my elem15, next lane's elem0): both
        // sides computed locally from the pre-issued shuffles.
#pragma unroll
        for (int r = 0; r < RPW; ++r) {
            // new elem15 = e^{i phi}(ct*e15 - st*next_e0)
            float ar = fmaf(-qq.y, nbr[r], qq.x * v[r][15].x);
            float ai = fmaf(-qq.y, nbi[r], qq.x * v[r][15].y);
            v[r][15].x = fmaf(-qq.w, ai, qq.z * ar);
            v[r][15].y = fmaf( qq.w, ar, qq.z * ai);
            // new elem0 = st'*prev_e15 + ct'*e0  (lane-1's pair, second row)
            float b0x = fmaf(qpx, v[r][0].x, qpy * pbr[r]);
            float b0y = fmaf(qpx, v[r][0].y, qpy * pbi[r]);
            v[r][0] = make_float2(b0x, b0y);
        }
    }

#pragma unroll
    for (int r = 0; r < RPW; ++r) {
        float4* dst = (float4*)(out + (size_t)(row0 + r) * (H_DIM * 2)) + lane * 8;
#pragma unroll
        for (int m = 0; m < 8; ++m) {
            dst[m] = make_float4(v[r][2 * m].x,     v[r][2 * m].y,
                                 v[r][2 * m + 1].x, v[r][2 * m + 1].y);
        }
    }
}

extern "C" void kernel_launch(void* const* d_in, const int* in_sizes, int n_in,
                              void* d_out, int out_size, void* d_ws, size_t ws_size,
                              hipStream_t stream) {
    const float* x      = (const float*)d_in[0];
    const float* phi0   = (const float*)d_in[1];
    const float* theta0 = (const float*)d_in[2];
    const float* phi1   = (const float*)d_in[3];
    const float* theta1 = (const float*)d_in[4];
    float* out = (float*)d_out;
    float4* coef = (float4*)d_ws;   // 256 layers * 16 * 64 float4 = 4 MB

    // coefficients: 256 layers * 2 phases * 512 pairs = 262144 threads
    hipLaunchKernelGGL(eunn_coef_kernel, dim3(1024), dim3(256), 0, stream,
                       phi0, theta0, phi1, theta1, coef);

    // main: 4096 rows / (4 waves/block * RPW rows/wave) = 512 blocks
    hipLaunchKernelGGL(eunn_main_kernel, dim3(512), dim3(256), 0, stream,
                       x, coef, out);
}